// Round 8
// baseline (325.549 us; speedup 1.0000x reference)
//
#include <hip/hip_runtime.h>
#include <hip/hip_bf16.h>
#include <cstdint>
#include <cstddef>

// Problem constants (fixed shapes per reference)
#define NROWS 8192
#define DIM   1024
#define BM 128
#define BN 128
#define BK 64             // K depth per iteration; 16 iterations
#define NITER (DIM / BK)
#define NTILE (NROWS / BM)   // 64 strips of 128 rows
#define NBLK  2080           // 64*65/2 triangle tiles = 8 XCDs x 260
#define EPS 1e-8f
// E pre-scaled by sqrt(10*log2(e)) so MFMA accumulates 10*log2(e)*<a,b>;
// epilogue is a bare exp2f.
#define PRESCALE 3.798288f

typedef short  bf16x8  __attribute__((ext_vector_type(8)));
typedef float  floatx4 __attribute__((ext_vector_type(4)));

typedef __attribute__((address_space(1))) const void CGV;
typedef __attribute__((address_space(3))) void LV;

__device__ __forceinline__ void async_load16(const void* g, void* l) {
    __builtin_amdgcn_global_load_lds((CGV*)g, (LV*)l, 16, 0, 0);
}

__device__ __forceinline__ unsigned short f2bf_rne(float f) {
    union { float f; unsigned u; } c; c.f = f;
    unsigned u = c.u;
    unsigned r = (u + 0x7fffu + ((u >> 16) & 1u)) >> 16;
    return (unsigned short)r;
}

// ---------------------------------------------------------------------------
// Kernel A: fp32 -> bf16 (RNE) with PRESCALE folded in. First 64 blocks also
// zero the accumulator region; block 64 zeros the finalize ticket.
// ---------------------------------------------------------------------------
__global__ __launch_bounds__(256) void convert_kernel(
    const float* __restrict__ in, unsigned short* __restrict__ out,
    float* __restrict__ accum /* all_sum ++ pos_sum */, int* __restrict__ ticket)
{
    int i = (blockIdx.x * 256 + threadIdx.x) * 4;
    float4 v = *(const float4*)(in + i);
    ushort4 o;
    o.x = f2bf_rne(v.x * PRESCALE);
    o.y = f2bf_rne(v.y * PRESCALE);
    o.z = f2bf_rne(v.z * PRESCALE);
    o.w = f2bf_rne(v.w * PRESCALE);
    *(ushort4*)(out + i) = o;
    if (blockIdx.x < (2 * NROWS) / 256)
        accum[blockIdx.x * 256 + threadIdx.x] = 0.0f;
    if (blockIdx.x == 64 && threadIdx.x == 0)
        *ticket = 0;
}

// ---------------------------------------------------------------------------
// Kernel B: symmetric-half fused GEMM (R3-proven K-loop) + XCD-local tile
// order + fused finalize.
//
// Tile schedule: paired strips — virtual strip k holds rows bi=k (k+1 tiles)
// and bi=63-k (64-k tiles) = 65 tiles, balancing the triangle. XCD x
// (heuristic: blockIdx%8) owns strips {4x..4x+3} -> 8 contiguous A-panels
// (2 MB); within an XCD tiles are bj-major so consecutive blocks share one
// B-panel (0.25 MB) -> ~2.25 MB L2 working set vs 4 MB per-XCD L2.
//
// K-loop: global_load_lds width 16, 2 barriers/iter (R3: 137 us, 0 bank
// conflicts with chunk swizzle c' = c ^ (row&7)).
// Off-diagonal tiles feed row- AND col-reduces (symmetry); diag masks j==i.
// Last block (atomic ticket) runs the finalize reduction inline.
// ---------------------------------------------------------------------------
__global__ __launch_bounds__(256, 5) void gemm_fused_kernel(
    const unsigned short* __restrict__ E,   // bf16 bits (prescaled), [NROWS][DIM]
    const int*            __restrict__ labels,
    float*                __restrict__ all_sum,
    float*                __restrict__ pos_sum,
    int*                  __restrict__ ticket,
    float*                __restrict__ out)
{
    __shared__ __align__(16) unsigned short sA[BM * BK];   // 16 KB
    __shared__ __align__(16) unsigned short sB[BN * BK];   // 16 KB
    __shared__ int sTicket;

    const int tid  = threadIdx.x;
    const int lane = tid & 63;
    const int w    = tid >> 6;
    const int wm   = w >> 1;        // wave row (0..1) -> 64 rows
    const int wn   = w & 1;         // wave col (0..1) -> 64 cols
    const int colw = lane & 15;
    const int quad = lane >> 4;

    // ---- tile decode: XCD-local, bj-major over 4 paired strips ----
    const int b  = blockIdx.x;
    const int x  = b & 7;          // assumed XCD id (perf heuristic only)
    int       p  = b >> 3;         // 0..259 within XCD
    const int k0 = x << 2;         // strips k0..k0+3
    int bi = 0, bj = 0;
    for (;;) {
        int lo = (k0 + 4) - ((bj > k0) ? bj : k0);          // #lower bi=k>=bj
        lo = (lo < 0) ? 0 : ((lo > 4) ? 4 : lo);
        int up = 64 - bj - k0;                              // #upper bi=63-k, k<=63-bj
        up = (up < 0) ? 0 : ((up > 4) ? 4 : up);
        const int c = lo + up;
        if (p < c) {
            if (p < lo) bi = ((bj > k0) ? bj : k0) + p;
            else        bi = 63 - (k0 + (p - lo));
            break;
        }
        p -= c; ++bj;
    }

    const int rBase = bi * BM;      // rows (A tile)
    const int cBase = bj * BN;      // cols (B tile)
    const bool diag = (bi == bj);

    // Staging: tile = 128x64 = 1024 chunks of 16B; thread t owns LDS chunks
    // t + 256j (rows srow + 32j). Swizzled placement: global chunk
    // c = (t&7) ^ (srow&7); srow&7 invariant under +32.
    const int srow = tid >> 3;
    const int scol = (((tid & 7) ^ (srow & 7)) << 3);  // element col in 0..63
    const int e0   = tid * 8;                          // LDS elem offset chunk0

    floatx4 acc[4][4];
    #pragma unroll
    for (int i = 0; i < 4; ++i)
        #pragma unroll
        for (int j = 0; j < 4; ++j)
            acc[i][j] = (floatx4)0.0f;

    // Fragment reads: chunk (h*4+quad) stored at slot ^ (row&7) = ^ (colw&7).
    const int swz   = colw & 7;
    const int aRow0 = (wm * 64 + colw) * BK;
    const int bRow0 = (wn * 64 + colw) * BK;

    const size_t gA0 = (size_t)(rBase + srow) * DIM + scol;
    const size_t gB0 = (size_t)(cBase + srow) * DIM + scol;
    const size_t rstep = (size_t)32 * DIM;

    for (int k0i = 0; k0i < DIM; k0i += BK) {
        __syncthreads();   // previous compute done before overwrite
        async_load16(E + gA0 + k0i,             &sA[e0]);
        async_load16(E + gA0 + rstep + k0i,     &sA[e0 + 2048]);
        async_load16(E + gA0 + 2 * rstep + k0i, &sA[e0 + 4096]);
        async_load16(E + gA0 + 3 * rstep + k0i, &sA[e0 + 6144]);
        async_load16(E + gB0 + k0i,             &sB[e0]);
        async_load16(E + gB0 + rstep + k0i,     &sB[e0 + 2048]);
        async_load16(E + gB0 + 2 * rstep + k0i, &sB[e0 + 4096]);
        async_load16(E + gB0 + 3 * rstep + k0i, &sB[e0 + 6144]);
        __syncthreads();   // vmcnt drained by compiler before barrier

        #pragma unroll
        for (int h = 0; h < 2; ++h) {
            const int cOff = (((h << 2) | quad) ^ swz) << 3;
            bf16x8 aF[4], bF[4];
            #pragma unroll
            for (int mt = 0; mt < 4; ++mt)
                aF[mt] = *(const bf16x8*)&sA[aRow0 + mt * 16 * BK + cOff];
            #pragma unroll
            for (int nt = 0; nt < 4; ++nt)
                bF[nt] = *(const bf16x8*)&sB[bRow0 + nt * 16 * BK + cOff];

            #pragma unroll
            for (int mt = 0; mt < 4; ++mt)
                #pragma unroll
                for (int nt = 0; nt < 4; ++nt)
                    acc[mt][nt] = __builtin_amdgcn_mfma_f32_16x16x32_bf16(
                        aF[mt], bF[nt], acc[mt][nt], 0, 0, 0);
        }
    }

    // Epilogue. C/D layout (16x16x32): col = lane&15, row = quad*4 + reg.
    float labc[4];
    int   gcol[4];
    #pragma unroll
    for (int nt = 0; nt < 4; ++nt) {
        gcol[nt] = cBase + wn * 64 + nt * 16 + colw;
        labc[nt] = (float)labels[gcol[nt]];
    }

    float colAll[4] = {0.f, 0.f, 0.f, 0.f};
    float colPos[4] = {0.f, 0.f, 0.f, 0.f};

    #pragma unroll
    for (int mt = 0; mt < 4; ++mt) {
        const int growBase = rBase + wm * 64 + mt * 16 + quad * 4;
        #pragma unroll
        for (int r = 0; r < 4; ++r) {
            const int grow = growBase + r;
            const float labr = (float)labels[grow];
            float sAll = 0.f, sPos = 0.f;
            #pragma unroll
            for (int nt = 0; nt < 4; ++nt) {
                float ev = exp2f(acc[mt][nt][r]);   // PRESCALE folded into E
                if (diag && grow == gcol[nt]) ev = 0.0f;  // exclude self
                sAll += ev;
                sPos += ev * labc[nt];
                colAll[nt] += ev;
                colPos[nt] += ev * labr;
            }
            #pragma unroll
            for (int off = 1; off < 16; off <<= 1) {
                sAll += __shfl_xor(sAll, off);
                sPos += __shfl_xor(sPos, off);
            }
            if (colw == 0) {
                atomicAdd(&all_sum[grow], sAll);
                atomicAdd(&pos_sum[grow], sPos);
            }
        }
    }

    if (!diag) {
        #pragma unroll
        for (int nt = 0; nt < 4; ++nt) {
            float a = colAll[nt], pq = colPos[nt];
            a += __shfl_xor(a, 16);  pq += __shfl_xor(pq, 16);
            a += __shfl_xor(a, 32);  pq += __shfl_xor(pq, 32);
            if (quad == 0) {
                atomicAdd(&all_sum[gcol[nt]], a);
                atomicAdd(&pos_sum[gcol[nt]], pq);
            }
        }
    }

    // ---- fused finalize: last block through the ticket does the reduction ----
    __threadfence();   // release: our atomics visible before ticket bump
    if (tid == 0) sTicket = atomicAdd(ticket, 1);
    __syncthreads();
    if (sTicket == NBLK - 1) {
        __threadfence();   // acquire: all other blocks' atomics visible
        float lsum = 0.f, lcnt = 0.f;
        for (int i = tid; i < NROWS; i += 256) {
            if (labels[i] > 0) {
                lsum += -logf(pos_sum[i] / (all_sum[i] + EPS));
                lcnt += 1.0f;
            }
        }
        #pragma unroll
        for (int off = 1; off < 64; off <<= 1) {
            lsum += __shfl_xor(lsum, off);
            lcnt += __shfl_xor(lcnt, off);
        }
        float* red = (float*)sA;   // LDS reuse after K-loop
        if (lane == 0) { red[w * 2] = lsum; red[w * 2 + 1] = lcnt; }
        __syncthreads();
        if (tid == 0) {
            float S = 0.f, C = 0.f;
            #pragma unroll
            for (int j = 0; j < 4; ++j) { S += red[j * 2]; C += red[j * 2 + 1]; }
            out[0] = (C < 2.0f) ? 0.0f : S / fmaxf(C, 1.0f);
        }
    }
}

// ---------------------------------------------------------------------------
extern "C" void kernel_launch(void* const* d_in, const int* in_sizes, int n_in,
                              void* d_out, int out_size, void* d_ws, size_t ws_size,
                              hipStream_t stream) {
    const float* emb    = (const float*)d_in[0];
    const int*   labels = (const int*)d_in[1];
    float*       out    = (float*)d_out;

    // workspace: [bf16 E: 16 MB][all_sum: 32 KB][pos_sum: 32 KB][ticket: 4 B]
    unsigned short* Ebf = (unsigned short*)d_ws;
    const size_t embBytes = (size_t)NROWS * DIM * sizeof(unsigned short);
    float* all_sum = (float*)((char*)d_ws + embBytes);
    float* pos_sum = all_sum + NROWS;
    int*   ticket  = (int*)(pos_sum + NROWS);

    convert_kernel<<<(NROWS * DIM) / (4 * 256), 256, 0, stream>>>(emb, Ebf, all_sum, ticket);

    gemm_fused_kernel<<<NBLK, 256, 0, stream>>>(Ebf, labels, all_sum, pos_sum, ticket, out);
}

// Round 9
// 210.470 us; speedup vs baseline: 1.5468x; 1.5468x over previous
//
#include <hip/hip_runtime.h>
#include <hip/hip_bf16.h>
#include <cstdint>
#include <cstddef>

// Problem constants (fixed shapes per reference)
#define NROWS 8192
#define DIM   1024
#define BM 128
#define BN 128
#define BK 64             // K depth per iteration; 16 iterations
#define EPS 1e-8f
// E pre-scaled by sqrt(10*log2(e)) so MFMA accumulates 10*log2(e)*<a,b>;
// epilogue is a bare exp2f.
#define PRESCALE 3.798288f

typedef short  bf16x8  __attribute__((ext_vector_type(8)));
typedef float  floatx4 __attribute__((ext_vector_type(4)));

typedef __attribute__((address_space(1))) const void CGV;
typedef __attribute__((address_space(3))) void LV;

__device__ __forceinline__ void async_load16(const void* g, void* l) {
    __builtin_amdgcn_global_load_lds((CGV*)g, (LV*)l, 16, 0, 0);
}

__device__ __forceinline__ unsigned short f2bf_rne(float f) {
    union { float f; unsigned u; } c; c.f = f;
    unsigned u = c.u;
    unsigned r = (u + 0x7fffu + ((u >> 16) & 1u)) >> 16;
    return (unsigned short)r;
}

// ---------------------------------------------------------------------------
// Kernel A: fp32 -> bf16 (RNE) with PRESCALE folded in. First 64 blocks also
// zero the 16384-float accumulator region (replaces a memset dispatch).
// ---------------------------------------------------------------------------
__global__ __launch_bounds__(256) void convert_kernel(
    const float* __restrict__ in, unsigned short* __restrict__ out,
    float* __restrict__ accum /* all_sum ++ pos_sum, 2*NROWS floats */)
{
    int i = (blockIdx.x * 256 + threadIdx.x) * 4;
    float4 v = *(const float4*)(in + i);
    ushort4 o;
    o.x = f2bf_rne(v.x * PRESCALE);
    o.y = f2bf_rne(v.y * PRESCALE);
    o.z = f2bf_rne(v.z * PRESCALE);
    o.w = f2bf_rne(v.w * PRESCALE);
    *(ushort4*)(out + i) = o;
    if (blockIdx.x < (2 * NROWS) / 256)
        accum[blockIdx.x * 256 + threadIdx.x] = 0.0f;
}

// ---------------------------------------------------------------------------
// Kernel B: symmetric-half fused GEMM — EXACT R3-proven K-loop (137 us,
// 0 bank conflicts, VGPR 64) with ONE change: XCD-local tile order.
// t = (b&7)*260 + (b>>3): blocks are dispatched round-robin over the 8 XCDs
// (heuristic), so XCD x executes a CONTIGUOUS run of 260 bi-major triangle
// tiles -> few A-panels (0.25 MB each) stay L2-resident while B-panels
// stream; working set ~2 MB vs 4 MB per-XCD L2. R8 measured this schedule
// class cutting FETCH 235->56 MB; here it runs without R8's fence/ticket and
// register damage.
// Off-diagonal tiles feed row- AND col-reduces (symmetry); diag masks j==i.
// ---------------------------------------------------------------------------
__global__ __launch_bounds__(256, 4) void gemm_fused_kernel(
    const unsigned short* __restrict__ E,   // bf16 bits (prescaled), [NROWS][DIM]
    const int*            __restrict__ labels,
    float*                __restrict__ all_sum,
    float*                __restrict__ pos_sum)
{
    __shared__ __align__(16) unsigned short sA[BM * BK];   // 16 KB
    __shared__ __align__(16) unsigned short sB[BN * BK];   // 16 KB

    const int tid  = threadIdx.x;
    const int lane = tid & 63;
    const int w    = tid >> 6;
    const int wm   = w >> 1;        // wave row (0..1) -> 64 rows
    const int wn   = w & 1;         // wave col (0..1) -> 64 cols
    const int colw = lane & 15;
    const int quad = lane >> 4;

    // XCD-local linear tile id, then sqrt triangle decode (R3-proven).
    const int b = blockIdx.x;
    const int t = (b & 7) * 260 + (b >> 3);     // 2080 = 8 x 260
    int bi = (int)((sqrtf(8.0f * (float)t + 1.0f) - 1.0f) * 0.5f);
    while ((bi + 1) * (bi + 2) / 2 <= t) ++bi;
    while (bi * (bi + 1) / 2 > t) --bi;
    const int bj = t - bi * (bi + 1) / 2;

    const int rBase = bi * BM;      // rows (A tile)
    const int cBase = bj * BN;      // cols (B tile)
    const bool diag = (bi == bj);

    // Staging: tile = 128x64 = 1024 chunks of 16B; thread t owns LDS chunks
    // t + 256j (rows srow + 32j). Swizzled placement: global chunk
    // c = (t&7) ^ (srow&7); srow&7 invariant under +32.
    const int srow = tid >> 3;
    const int scol = (((tid & 7) ^ (srow & 7)) << 3);  // element col in 0..63
    const int e0   = tid * 8;                          // LDS elem offset chunk0

    floatx4 acc[4][4];
    #pragma unroll
    for (int i = 0; i < 4; ++i)
        #pragma unroll
        for (int j = 0; j < 4; ++j)
            acc[i][j] = (floatx4)0.0f;

    // Fragment reads: chunk (h*4+quad) stored at slot ^ (row&7) = ^ (colw&7).
    const int swz   = colw & 7;
    const int aRow0 = (wm * 64 + colw) * BK;
    const int bRow0 = (wn * 64 + colw) * BK;

    const size_t gA0 = (size_t)(rBase + srow) * DIM + scol;
    const size_t gB0 = (size_t)(cBase + srow) * DIM + scol;
    const size_t rstep = (size_t)32 * DIM;

    for (int k0 = 0; k0 < DIM; k0 += BK) {
        __syncthreads();   // previous compute done before overwrite
        async_load16(E + gA0 + k0,             &sA[e0]);
        async_load16(E + gA0 + rstep + k0,     &sA[e0 + 2048]);
        async_load16(E + gA0 + 2 * rstep + k0, &sA[e0 + 4096]);
        async_load16(E + gA0 + 3 * rstep + k0, &sA[e0 + 6144]);
        async_load16(E + gB0 + k0,             &sB[e0]);
        async_load16(E + gB0 + rstep + k0,     &sB[e0 + 2048]);
        async_load16(E + gB0 + 2 * rstep + k0, &sB[e0 + 4096]);
        async_load16(E + gB0 + 3 * rstep + k0, &sB[e0 + 6144]);
        __syncthreads();   // vmcnt drained by compiler before barrier

        #pragma unroll
        for (int h = 0; h < 2; ++h) {
            const int cOff = (((h << 2) | quad) ^ swz) << 3;
            bf16x8 aF[4], bF[4];
            #pragma unroll
            for (int mt = 0; mt < 4; ++mt)
                aF[mt] = *(const bf16x8*)&sA[aRow0 + mt * 16 * BK + cOff];
            #pragma unroll
            for (int nt = 0; nt < 4; ++nt)
                bF[nt] = *(const bf16x8*)&sB[bRow0 + nt * 16 * BK + cOff];

            #pragma unroll
            for (int mt = 0; mt < 4; ++mt)
                #pragma unroll
                for (int nt = 0; nt < 4; ++nt)
                    acc[mt][nt] = __builtin_amdgcn_mfma_f32_16x16x32_bf16(
                        aF[mt], bF[nt], acc[mt][nt], 0, 0, 0);
        }
    }

    // Epilogue. C/D layout (16x16x32): col = lane&15, row = quad*4 + reg.
    float labc[4];
    int   gcol[4];
    #pragma unroll
    for (int nt = 0; nt < 4; ++nt) {
        gcol[nt] = cBase + wn * 64 + nt * 16 + colw;
        labc[nt] = (float)labels[gcol[nt]];
    }

    float colAll[4] = {0.f, 0.f, 0.f, 0.f};
    float colPos[4] = {0.f, 0.f, 0.f, 0.f};

    #pragma unroll
    for (int mt = 0; mt < 4; ++mt) {
        const int growBase = rBase + wm * 64 + mt * 16 + quad * 4;
        #pragma unroll
        for (int r = 0; r < 4; ++r) {
            const int grow = growBase + r;
            const float labr = (float)labels[grow];
            float sAll = 0.f, sPos = 0.f;
            #pragma unroll
            for (int nt = 0; nt < 4; ++nt) {
                float ev = exp2f(acc[mt][nt][r]);   // PRESCALE folded into E
                if (diag && grow == gcol[nt]) ev = 0.0f;  // exclude self
                sAll += ev;
                sPos += ev * labc[nt];
                colAll[nt] += ev;
                colPos[nt] += ev * labr;
            }
            // row-reduce across the 16 lanes (same quad) sharing this row
            #pragma unroll
            for (int off = 1; off < 16; off <<= 1) {
                sAll += __shfl_xor(sAll, off);
                sPos += __shfl_xor(sPos, off);
            }
            if (colw == 0) {
                atomicAdd(&all_sum[grow], sAll);
                atomicAdd(&pos_sum[grow], sPos);
            }
        }
    }

    if (!diag) {
        // col-reduce: sum across quads (lanes differing in bits 4,5)
        #pragma unroll
        for (int nt = 0; nt < 4; ++nt) {
            float a = colAll[nt], p = colPos[nt];
            a += __shfl_xor(a, 16);  p += __shfl_xor(p, 16);
            a += __shfl_xor(a, 32);  p += __shfl_xor(p, 32);
            if (quad == 0) {
                atomicAdd(&all_sum[gcol[nt]], a);
                atomicAdd(&pos_sum[gcol[nt]], p);
            }
        }
    }
}

// ---------------------------------------------------------------------------
// Kernel C: loss = mean over rows with lab==1 of -log(pos/(all+eps)); 0 if n_ref<2
// ---------------------------------------------------------------------------
__global__ __launch_bounds__(1024) void finalize_kernel(
    const float* __restrict__ all_sum,
    const float* __restrict__ pos_sum,
    const int*   __restrict__ labels,
    float*       __restrict__ out)
{
    __shared__ float sSum[1024];
    __shared__ float sCnt[1024];
    const int tid = threadIdx.x;
    float lsum = 0.f, lcnt = 0.f;
    for (int i = tid; i < NROWS; i += 1024) {
        if (labels[i] > 0) {
            float p = pos_sum[i];
            float a = all_sum[i] + EPS;
            lsum += -logf(p / a);
            lcnt += 1.0f;
        }
    }
    sSum[tid] = lsum;
    sCnt[tid] = lcnt;
    __syncthreads();
    for (int s = 512; s > 0; s >>= 1) {
        if (tid < s) { sSum[tid] += sSum[tid + s]; sCnt[tid] += sCnt[tid + s]; }
        __syncthreads();
    }
    if (tid == 0) {
        float n = sCnt[0];
        out[0] = (n < 2.0f) ? 0.0f : sSum[0] / fmaxf(n, 1.0f);
    }
}

// ---------------------------------------------------------------------------
extern "C" void kernel_launch(void* const* d_in, const int* in_sizes, int n_in,
                              void* d_out, int out_size, void* d_ws, size_t ws_size,
                              hipStream_t stream) {
    const float* emb    = (const float*)d_in[0];
    const int*   labels = (const int*)d_in[1];
    float*       out    = (float*)d_out;

    // workspace layout: [bf16 E: 16 MB][all_sum: 32 KB][pos_sum: 32 KB]
    unsigned short* Ebf = (unsigned short*)d_ws;
    const size_t embBytes = (size_t)NROWS * DIM * sizeof(unsigned short);
    float* all_sum = (float*)((char*)d_ws + embBytes);
    float* pos_sum = all_sum + NROWS;

    convert_kernel<<<(NROWS * DIM) / (4 * 256), 256, 0, stream>>>(emb, Ebf, all_sum);

    const int nBlocksTri = (NROWS / BM) * (NROWS / BM + 1) / 2;  // 64*65/2 = 2080
    gemm_fused_kernel<<<nBlocksTri, 256, 0, stream>>>(Ebf, labels, all_sum, pos_sum);

    finalize_kernel<<<1, 1024, 0, stream>>>(all_sum, pos_sum, labels, out);
}